// Round 1
// baseline (212.009 us; speedup 1.0000x reference)
//
#include <hip/hip_runtime.h>
#include <stdint.h>

#define B_ 4
#define T_ 2048
#define S_ 2048
#define E_ 512
#define H_ 8
#define D_ 64

using bf16x8 = __attribute__((ext_vector_type(8))) short;
using f32x4  = __attribute__((ext_vector_type(4))) float;

__device__ __forceinline__ unsigned short f2bf(float f) {
  unsigned u = __float_as_uint(f);
  u += 0x7fffu + ((u >> 16) & 1u);          // round-to-nearest-even
  return (unsigned short)(u >> 16);
}

__device__ __forceinline__ float sigmoidf_(float x) {
  return 1.0f / (1.0f + __expf(-x));
}

// async global->LDS, 16B per lane. LDS dest = wave-uniform base + lane*16.
__device__ __forceinline__ void gl16(const void* g, void* l) {
  __builtin_amdgcn_global_load_lds(
      (const __attribute__((address_space(1))) unsigned*)g,
      (__attribute__((address_space(3))) unsigned*)l,
      16, 0, 0);
}

// ---------------------------------------------------------------- convert
__global__ __launch_bounds__(256) void cvt_bf16(const float* __restrict__ in,
                                                unsigned short* __restrict__ out,
                                                int n4) {
  int i = blockIdx.x * 256 + threadIdx.x;
  int stride = gridDim.x * 256;
  for (; i < n4; i += stride) {
    float4 v = ((const float4*)in)[i];
    ushort4 o;
    o.x = f2bf(v.x); o.y = f2bf(v.y); o.z = f2bf(v.z); o.w = f2bf(v.w);
    ((ushort4*)out)[i] = o;
  }
}

// ---------------------------------------------------------------- GEMM
// C[M,N] = A[M,512] * W[N,512]^T  (NT gemm, K=512), 128x128 tile, BK=64.
// EPI 0: logistic-map epilogue, bf16 stores to [B,H,T,D]    (Q / K proj)
// EPI 1: bias-by-row, bf16 stores to [B,H,D,S]              (V^T proj)
// EPI 2: bias-by-col, fp32 stores row-major                 (out proj)
#define EPI_LH  0
#define EPI_VT  1
#define EPI_F32 2

template <int EPI>
__global__ __launch_bounds__(256) void gemm_nt(
    const unsigned short* __restrict__ A,
    const unsigned short* __restrict__ W,
    const float* __restrict__ bias,
    void* __restrict__ outp,
    const float* __restrict__ rptr,
    int M, int N, int nTN) {
  __shared__ unsigned short As[2][128 * 64];
  __shared__ unsigned short Bs[2][128 * 64];

  int tid = threadIdx.x;
  int lane = tid & 63, wid = tid >> 6;
  int bm = blockIdx.x / nTN, bn = blockIdx.x % nTN;
  int m0 = bm * 128, n0 = bn * 128;

  f32x4 acc[4][4] = {};

  int rowc = tid >> 3;          // 0..31 rows per 4KB chunk
  int kcol = (tid & 7) * 8;     // bf16 elems into the 64-wide k window

  auto stage = [&](int buf, int kt) {
#pragma unroll
    for (int c = 0; c < 4; ++c) {
      const unsigned short* ga = A + (size_t)(m0 + c * 32 + rowc) * 512 + kt * 64 + kcol;
      const unsigned short* gw = W + (size_t)(n0 + c * 32 + rowc) * 512 + kt * 64 + kcol;
      gl16(ga, (char*)&As[buf][0] + c * 4096 + (wid << 10));
      gl16(gw, (char*)&Bs[buf][0] + c * 4096 + (wid << 10));
    }
  };

  stage(0, 0);

  int wm = wid >> 1, wn = wid & 1;       // 2x2 waves, 64x64 each
  int fr = lane & 15, fg = lane >> 4;

  for (int kt = 0; kt < 8; ++kt) {
    __syncthreads();                     // staged tile `kt` ready (vmcnt drained)
    if (kt < 7) stage((kt + 1) & 1, kt + 1);
    int buf = kt & 1;
#pragma unroll
    for (int ks = 0; ks < 2; ++ks) {
      bf16x8 a[4], b[4];
#pragma unroll
      for (int mi = 0; mi < 4; ++mi)
        a[mi] = *(const bf16x8*)&As[buf][(wm * 64 + mi * 16 + fr) * 64 + ks * 32 + fg * 8];
#pragma unroll
      for (int ni = 0; ni < 4; ++ni)
        b[ni] = *(const bf16x8*)&Bs[buf][(wn * 64 + ni * 16 + fr) * 64 + ks * 32 + fg * 8];
#pragma unroll
      for (int mi = 0; mi < 4; ++mi)
#pragma unroll
        for (int ni = 0; ni < 4; ++ni)
          acc[mi][ni] = __builtin_amdgcn_mfma_f32_16x16x32_bf16(a[mi], b[ni], acc[mi][ni], 0, 0, 0);
    }
  }

  float rs = 0.f;
  if constexpr (EPI == EPI_LH) rs = 4.0f * sigmoidf_(rptr[0]);

#pragma unroll
  for (int mi = 0; mi < 4; ++mi) {
#pragma unroll
    for (int ni = 0; ni < 4; ++ni) {
#pragma unroll
      for (int i = 0; i < 4; ++i) {
        int gm = m0 + wm * 64 + mi * 16 + fg * 4 + i;   // C row
        int gn = n0 + wn * 64 + ni * 16 + fr;           // C col
        float x = acc[mi][ni][i];
        if constexpr (EPI == EPI_LH) {
          x += bias[gn];
          float xn = sigmoidf_(x);
          float val = rs * xn * (1.0f - xn);
          int b = gm >> 11, t = gm & 2047, h = gn >> 6, d = gn & 63;
          ((unsigned short*)outp)[((size_t)(b * H_ + h) * T_ + t) * D_ + d] = f2bf(val);
        } else if constexpr (EPI == EPI_VT) {
          x += bias[gm];                                // bias indexed by e = row
          int h = gm >> 6, d = gm & 63, b = gn >> 11, s = gn & 2047;
          ((unsigned short*)outp)[((size_t)(b * H_ + h) * D_ + d) * S_ + s] = f2bf(x);
        } else {
          x += bias[gn];
          ((float*)outp)[(size_t)gm * E_ + gn] = x;
        }
      }
    }
  }
}

// ---------------------------------------------------------------- flash attention
// grid: 512 blocks = 32 (b,h) * 16 Q-tiles of 128 rows. 4 waves * 32 rows.
__global__ __launch_bounds__(256) void attn_flash(
    const unsigned short* __restrict__ qp,   // [B,H,T,D]
    const unsigned short* __restrict__ kp,   // [B,H,S,D]
    const unsigned short* __restrict__ vtp,  // [B,H,D,S]
    unsigned short* __restrict__ attno) {    // [B*T, E]
  __shared__ unsigned short Qs[128 * 64];
  __shared__ unsigned short Ks[2][64 * 64];
  __shared__ unsigned short Vs[2][64 * 64];  // V^T tile: [d][s]
  __shared__ unsigned short Ps[128 * 64];

  int tid = threadIdx.x, lane = tid & 63, wid = tid >> 6;
  int tt = blockIdx.x & 15, bh = blockIdx.x >> 4;
  const unsigned short* qh = qp + (size_t)bh * T_ * D_ + (size_t)tt * 128 * D_;
  const unsigned short* kh = kp + (size_t)bh * S_ * D_;
  const unsigned short* vh = vtp + (size_t)bh * D_ * S_;

  // stage Q: 16KB contiguous
#pragma unroll
  for (int c = 0; c < 4; ++c)
    gl16((const char*)qh + c * 4096 + tid * 16, (char*)Qs + c * 4096 + (wid << 10));

  auto stageKV = [&](int buf, int it) {
#pragma unroll
    for (int c = 0; c < 2; ++c)  // K tile: contiguous 8KB
      gl16((const char*)kh + it * 8192 + c * 4096 + tid * 16,
           (char*)&Ks[buf][0] + c * 4096 + (wid << 10));
#pragma unroll
    for (int c = 0; c < 2; ++c) {  // V^T tile: 64 rows of 128B, row stride S*2
      int o = c * 4096 + tid * 16;
      int d = o >> 7, scb = o & 127;  // byte offset within row
      gl16((const char*)vh + (size_t)d * (S_ * 2) + it * 128 + scb,
           (char*)&Vs[buf][0] + c * 4096 + (wid << 10));
    }
  };

  stageKV(0, 0);

  f32x4 acco[2][4] = {};
  float mst[2][4], lst[2][4];
#pragma unroll
  for (int mi = 0; mi < 2; ++mi)
#pragma unroll
    for (int i = 0; i < 4; ++i) { mst[mi][i] = -1e30f; lst[mi][i] = 0.f; }

  int fr = lane & 15, fg = lane >> 4;
  int qrb = wid * 32;

  for (int it = 0; it < 32; ++it) {
    __syncthreads();
    if (it < 31) stageKV((it + 1) & 1, it + 1);
    int buf = it & 1;

    // ---- S = Q K^T (scaled later)
    f32x4 sc[2][4] = {};
    bf16x8 qa[2][2], kb[4][2];
#pragma unroll
    for (int mi = 0; mi < 2; ++mi)
#pragma unroll
      for (int ks = 0; ks < 2; ++ks)
        qa[mi][ks] = *(const bf16x8*)&Qs[(qrb + mi * 16 + fr) * 64 + ks * 32 + fg * 8];
#pragma unroll
    for (int ni = 0; ni < 4; ++ni)
#pragma unroll
      for (int ks = 0; ks < 2; ++ks)
        kb[ni][ks] = *(const bf16x8*)&Ks[buf][(ni * 16 + fr) * 64 + ks * 32 + fg * 8];
#pragma unroll
    for (int mi = 0; mi < 2; ++mi)
#pragma unroll
      for (int ni = 0; ni < 4; ++ni)
#pragma unroll
        for (int ks = 0; ks < 2; ++ks)
          sc[mi][ni] = __builtin_amdgcn_mfma_f32_16x16x32_bf16(qa[mi][ks], kb[ni][ks], sc[mi][ni], 0, 0, 0);

    // ---- online softmax (wave-parallel row reduce over 16 lanes)
    float alpha[2][4];
#pragma unroll
    for (int mi = 0; mi < 2; ++mi) {
#pragma unroll
      for (int i = 0; i < 4; ++i) {
        float s0 = sc[mi][0][i] * 0.125f, s1 = sc[mi][1][i] * 0.125f;
        float s2 = sc[mi][2][i] * 0.125f, s3 = sc[mi][3][i] * 0.125f;
        float rmax = fmaxf(fmaxf(s0, s1), fmaxf(s2, s3));
#pragma unroll
        for (int x = 1; x < 16; x <<= 1) rmax = fmaxf(rmax, __shfl_xor(rmax, x));
        float mold = mst[mi][i];
        float mnew = fmaxf(mold, rmax);
        float a_ = __expf(mold - mnew);
        float p0 = __expf(s0 - mnew), p1 = __expf(s1 - mnew);
        float p2 = __expf(s2 - mnew), p3 = __expf(s3 - mnew);
        float rsum = (p0 + p1) + (p2 + p3);
#pragma unroll
        for (int x = 1; x < 16; x <<= 1) rsum += __shfl_xor(rsum, x);
        mst[mi][i] = mnew;
        lst[mi][i] = lst[mi][i] * a_ + rsum;
        alpha[mi][i] = a_;
        int prow = qrb + mi * 16 + fg * 4 + i;
        Ps[prow * 64 +  0 + fr] = f2bf(p0);
        Ps[prow * 64 + 16 + fr] = f2bf(p1);
        Ps[prow * 64 + 32 + fr] = f2bf(p2);
        Ps[prow * 64 + 48 + fr] = f2bf(p3);
      }
    }
#pragma unroll
    for (int mi = 0; mi < 2; ++mi)
#pragma unroll
      for (int ni = 0; ni < 4; ++ni)
#pragma unroll
        for (int i = 0; i < 4; ++i) acco[mi][ni][i] *= alpha[mi][i];

    // ---- O += P V   (A = P from LDS, B = V^T rows)
    bf16x8 pa[2][2], vb[4][2];
#pragma unroll
    for (int mi = 0; mi < 2; ++mi)
#pragma unroll
      for (int ks = 0; ks < 2; ++ks)
        pa[mi][ks] = *(const bf16x8*)&Ps[(qrb + mi * 16 + fr) * 64 + ks * 32 + fg * 8];
#pragma unroll
    for (int ni = 0; ni < 4; ++ni)
#pragma unroll
      for (int ks = 0; ks < 2; ++ks)
        vb[ni][ks] = *(const bf16x8*)&Vs[buf][(ni * 16 + fr) * 64 + ks * 32 + fg * 8];
#pragma unroll
    for (int mi = 0; mi < 2; ++mi)
#pragma unroll
      for (int ni = 0; ni < 4; ++ni)
#pragma unroll
        for (int ks = 0; ks < 2; ++ks)
          acco[mi][ni] = __builtin_amdgcn_mfma_f32_16x16x32_bf16(pa[mi][ks], vb[ni][ks], acco[mi][ni], 0, 0, 0);
  }

  // ---- epilogue: O /= l, store bf16 to [b*T+t, h*64+d]
  int b = bh >> 3, h = bh & 7;
#pragma unroll
  for (int mi = 0; mi < 2; ++mi)
#pragma unroll
    for (int ni = 0; ni < 4; ++ni)
#pragma unroll
      for (int i = 0; i < 4; ++i) {
        int t = tt * 128 + qrb + mi * 16 + fg * 4 + i;
        int d = ni * 16 + fr;
        float o = acco[mi][ni][i] / lst[mi][i];
        attno[(size_t)(b * T_ + t) * E_ + h * 64 + d] = f2bf(o);
      }
}

// ---------------------------------------------------------------- launch
extern "C" void kernel_launch(void* const* d_in, const int* in_sizes, int n_in,
                              void* d_out, int out_size, void* d_ws, size_t ws_size,
                              hipStream_t stream) {
  const float* query = (const float*)d_in[0];
  const float* key_  = (const float*)d_in[1];
  const float* value = (const float*)d_in[2];
  const float* Wq    = (const float*)d_in[3];
  const float* bq    = (const float*)d_in[4];
  const float* Wk    = (const float*)d_in[5];
  const float* bk    = (const float*)d_in[6];
  const float* Wv    = (const float*)d_in[7];
  const float* bv    = (const float*)d_in[8];
  const float* Wo    = (const float*)d_in[9];
  const float* bo    = (const float*)d_in[10];
  const float* r     = (const float*)d_in[11];

  char* ws = (char*)d_ws;
  unsigned short* qb    = (unsigned short*)(ws + 0);          //  8 MiB  query bf16
  unsigned short* kb    = (unsigned short*)(ws + 8388608);    //  8 MiB  key bf16
  unsigned short* vb    = (unsigned short*)(ws + 16777216);   //  8 MiB  value bf16
  unsigned short* wqb   = (unsigned short*)(ws + 25165824);   // 512 KiB
  unsigned short* wkb   = (unsigned short*)(ws + 25690112);
  unsigned short* wvb   = (unsigned short*)(ws + 26214400);
  unsigned short* wob   = (unsigned short*)(ws + 26738688);
  unsigned short* qp    = (unsigned short*)(ws + 27262976);   //  8 MiB  [B,H,T,D]
  unsigned short* kp    = (unsigned short*)(ws + 35651584);   //  8 MiB  [B,H,S,D]
  unsigned short* vtp   = (unsigned short*)(ws + 44040192);   //  8 MiB  [B,H,D,S]
  unsigned short* attno = (unsigned short*)(ws + 52428800);   //  8 MiB  [B*T, E]

  cvt_bf16<<<2048, 256, 0, stream>>>(query, qb, (B_ * T_ * E_) / 4);
  cvt_bf16<<<2048, 256, 0, stream>>>(key_,  kb, (B_ * S_ * E_) / 4);
  cvt_bf16<<<2048, 256, 0, stream>>>(value, vb, (B_ * S_ * E_) / 4);
  cvt_bf16<<<256, 256, 0, stream>>>(Wq, wqb, (E_ * E_) / 4);
  cvt_bf16<<<256, 256, 0, stream>>>(Wk, wkb, (E_ * E_) / 4);
  cvt_bf16<<<256, 256, 0, stream>>>(Wv, wvb, (E_ * E_) / 4);
  cvt_bf16<<<256, 256, 0, stream>>>(Wo, wob, (E_ * E_) / 4);

  // Q = logistic(query Wq^T + bq)  -> [B,H,T,D]
  gemm_nt<EPI_LH><<<256, 256, 0, stream>>>(qb, wqb, bq, qp, r, B_ * T_, E_, 4);
  // K = logistic(key Wk^T + bk)    -> [B,H,S,D]
  gemm_nt<EPI_LH><<<256, 256, 0, stream>>>(kb, wkb, bk, kp, r, B_ * S_, E_, 4);
  // V^T = Wv value^T + bv          -> [B,H,D,S]  (swapped NT gemm)
  gemm_nt<EPI_VT><<<256, 256, 0, stream>>>(wvb, vb, bv, vtp, r, E_, B_ * S_, 64);

  attn_flash<<<512, 256, 0, stream>>>(qp, kp, vtp, attno);

  // out = attno Wo^T + bo  (fp32)
  gemm_nt<EPI_F32><<<256, 256, 0, stream>>>(attno, wob, bo, d_out, r, B_ * T_, E_, 4);
}

// Round 2
// 175.618 us; speedup vs baseline: 1.2072x; 1.2072x over previous
//
#include <hip/hip_runtime.h>
#include <stdint.h>

#define B_ 4
#define T_ 2048
#define S_ 2048
#define E_ 512
#define H_ 8
#define D_ 64

using bf16x8 = __attribute__((ext_vector_type(8))) short;
using f32x4  = __attribute__((ext_vector_type(4))) float;

__device__ __forceinline__ unsigned short f2bf(float f) {
  unsigned u = __float_as_uint(f);
  u += 0x7fffu + ((u >> 16) & 1u);          // round-to-nearest-even
  return (unsigned short)(u >> 16);
}

__device__ __forceinline__ float sigmoidf_(float x) {
  return 1.0f / (1.0f + __expf(-x));
}

// async global->LDS, 16B per lane. LDS dest = wave-uniform base + lane*16.
__device__ __forceinline__ void gl16(const void* g, void* l) {
  __builtin_amdgcn_global_load_lds(
      (const __attribute__((address_space(1))) unsigned*)g,
      (__attribute__((address_space(3))) unsigned*)l,
      16, 0, 0);
}

// T2 swizzle for [R][64 bf16] (128B-row) LDS tiles:
// physical byte-in-row = logical byte-in-row ^ ((row&7)<<4).
// Returns ushort index into a width-64 tile.
__device__ __forceinline__ int swzi(int row, int ebyte) {
  return row * 64 + ((ebyte ^ ((row & 7) << 4)) >> 1);
}

// ---------------------------------------------------------------- converts
__global__ __launch_bounds__(256) void cvt3_bf16(
    const float* __restrict__ a, const float* __restrict__ b, const float* __restrict__ c,
    unsigned short* __restrict__ oa, unsigned short* __restrict__ ob,
    unsigned short* __restrict__ oc, int n4) {
  int seg = blockIdx.x >> 9;
  const float* in = (seg == 0) ? a : (seg == 1) ? b : c;
  unsigned short* out = (seg == 0) ? oa : (seg == 1) ? ob : oc;
  int i = (blockIdx.x & 511) * 256 + threadIdx.x;
  for (; i < n4; i += 512 * 256) {
    float4 v = ((const float4*)in)[i];
    ushort4 o;
    o.x = f2bf(v.x); o.y = f2bf(v.y); o.z = f2bf(v.z); o.w = f2bf(v.w);
    ((ushort4*)out)[i] = o;
  }
}

__global__ __launch_bounds__(256) void cvt4_bf16(
    const float* __restrict__ a, const float* __restrict__ b,
    const float* __restrict__ c, const float* __restrict__ d,
    unsigned short* __restrict__ oa, unsigned short* __restrict__ ob,
    unsigned short* __restrict__ oc, unsigned short* __restrict__ od, int n4) {
  int seg = blockIdx.x >> 7;
  const float* in = (seg == 0) ? a : (seg == 1) ? b : (seg == 2) ? c : d;
  unsigned short* out = (seg == 0) ? oa : (seg == 1) ? ob : (seg == 2) ? oc : od;
  int i = (blockIdx.x & 127) * 256 + threadIdx.x;
  for (; i < n4; i += 128 * 256) {
    float4 v = ((const float4*)in)[i];
    ushort4 o;
    o.x = f2bf(v.x); o.y = f2bf(v.y); o.z = f2bf(v.z); o.w = f2bf(v.w);
    ((ushort4*)out)[i] = o;
  }
}

// ---------------------------------------------------------------- GEMM
// C[M,N] = A[M,512] * W[N,512]^T  (NT gemm, K=512), 128x128 tile, BK=64.
#define EPI_LH  0
#define EPI_VT  1
#define EPI_F32 2

template <int EPI>
__global__ __launch_bounds__(256) void gemm_nt(
    const unsigned short* __restrict__ A,
    const unsigned short* __restrict__ W,
    const float* __restrict__ bias,
    void* __restrict__ outp,
    const float* __restrict__ rptr,
    int M, int N, int nTN) {
  __shared__ unsigned short As[2][128 * 64];
  __shared__ unsigned short Bs[2][128 * 64];

  int tid = threadIdx.x;
  int lane = tid & 63, wid = tid >> 6;
  int bm = blockIdx.x / nTN, bn = blockIdx.x % nTN;
  int m0 = bm * 128, n0 = bn * 128;

  f32x4 acc[4][4] = {};

  int rowc = tid >> 3;                                  // tile-local row / chunk
  int kswz = ((tid & 7) ^ ((tid >> 3) & 7)) << 4;       // pre-swizzled source byte col

  auto stage = [&](int buf, int kt) {
#pragma unroll
    for (int c = 0; c < 4; ++c) {
      const char* ga = (const char*)A + (size_t)(m0 + c * 32 + rowc) * 1024 + kt * 128 + kswz;
      const char* gw = (const char*)W + (size_t)(n0 + c * 32 + rowc) * 1024 + kt * 128 + kswz;
      gl16(ga, (char*)&As[buf][0] + c * 4096 + (wid << 10));
      gl16(gw, (char*)&Bs[buf][0] + c * 4096 + (wid << 10));
    }
  };

  stage(0, 0);

  int wm = wid >> 1, wn = wid & 1;       // 2x2 waves, 64x64 each
  int fr = lane & 15, fg = lane >> 4;

  for (int kt = 0; kt < 8; ++kt) {
    __syncthreads();                     // staged tile `kt` ready (vmcnt drained)
    if (kt < 7) stage((kt + 1) & 1, kt + 1);
    int buf = kt & 1;
#pragma unroll
    for (int ks = 0; ks < 2; ++ks) {
      bf16x8 a[4], b[4];
#pragma unroll
      for (int mi = 0; mi < 4; ++mi)
        a[mi] = *(const bf16x8*)&As[buf][swzi(wm * 64 + mi * 16 + fr, ks * 64 + fg * 16)];
#pragma unroll
      for (int ni = 0; ni < 4; ++ni)
        b[ni] = *(const bf16x8*)&Bs[buf][swzi(wn * 64 + ni * 16 + fr, ks * 64 + fg * 16)];
#pragma unroll
      for (int mi = 0; mi < 4; ++mi)
#pragma unroll
        for (int ni = 0; ni < 4; ++ni)
          acc[mi][ni] = __builtin_amdgcn_mfma_f32_16x16x32_bf16(a[mi], b[ni], acc[mi][ni], 0, 0, 0);
    }
  }

  float rs = 0.f;
  if constexpr (EPI == EPI_LH) rs = 4.0f * sigmoidf_(rptr[0]);

#pragma unroll
  for (int mi = 0; mi < 4; ++mi) {
#pragma unroll
    for (int ni = 0; ni < 4; ++ni) {
#pragma unroll
      for (int i = 0; i < 4; ++i) {
        int gm = m0 + wm * 64 + mi * 16 + fg * 4 + i;   // C row
        int gn = n0 + wn * 64 + ni * 16 + fr;           // C col
        float x = acc[mi][ni][i];
        if constexpr (EPI == EPI_LH) {
          x += bias[gn];
          float xn = sigmoidf_(x);
          float val = rs * xn * (1.0f - xn);
          int b = gm >> 11, t = gm & 2047, h = gn >> 6, d = gn & 63;
          ((unsigned short*)outp)[((size_t)(b * H_ + h) * T_ + t) * D_ + d] = f2bf(val);
        } else if constexpr (EPI == EPI_VT) {
          x += bias[gm];                                // bias indexed by e = row
          int h = gm >> 6, d = gm & 63, b = gn >> 11, s = gn & 2047;
          ((unsigned short*)outp)[((size_t)(b * H_ + h) * D_ + d) * S_ + s] = f2bf(x);
        } else {
          x += bias[gn];
          ((float*)outp)[(size_t)gm * E_ + gn] = x;
        }
      }
    }
  }
}

// ---------------------------------------------------------------- flash attention
// grid: 512 blocks = 32 (b,h) * 16 Q-tiles of 128 rows. 4 waves * 32 rows.
__global__ __launch_bounds__(256) void attn_flash(
    const unsigned short* __restrict__ qp,   // [B,H,T,D]
    const unsigned short* __restrict__ kp,   // [B,H,S,D]
    const unsigned short* __restrict__ vtp,  // [B,H,D,S]
    unsigned short* __restrict__ attno) {    // [B*T, E]
  __shared__ unsigned short Qs[128 * 64];
  __shared__ unsigned short Ks[2][64 * 64];
  __shared__ unsigned short Vs[2][64 * 64];  // V^T tile: [d][s]
  __shared__ unsigned short Ps[128 * 64];

  int tid = threadIdx.x, lane = tid & 63, wid = tid >> 6;
  int tt = blockIdx.x & 15, bh = blockIdx.x >> 4;
  const unsigned short* qh = qp + (size_t)bh * T_ * D_ + (size_t)tt * 128 * D_;
  const unsigned short* kh = kp + (size_t)bh * S_ * D_;
  const unsigned short* vh = vtp + (size_t)bh * D_ * S_;

  int kswz = ((tid & 7) ^ ((tid >> 3) & 7)) << 4;       // pre-swizzled source byte col

  // stage Q (swizzled source -> linear LDS == swizzled logical layout)
#pragma unroll
  for (int c = 0; c < 4; ++c)
    gl16((const char*)qh + (size_t)(c * 32 + (tid >> 3)) * 128 + kswz,
         (char*)Qs + c * 4096 + (wid << 10));

  auto stageKV = [&](int buf, int it) {
#pragma unroll
    for (int c = 0; c < 2; ++c)  // K tile rows: [s][64d]
      gl16((const char*)kh + (size_t)(it * 64 + c * 32 + (tid >> 3)) * 128 + kswz,
           (char*)&Ks[buf][0] + c * 4096 + (wid << 10));
#pragma unroll
    for (int c = 0; c < 2; ++c) {  // V^T tile rows: [d][64s], row stride S*2 bytes
      int d = c * 32 + (tid >> 3);
      gl16((const char*)vh + (size_t)d * (S_ * 2) + it * 128 + kswz,
           (char*)&Vs[buf][0] + c * 4096 + (wid << 10));
    }
  };

  stageKV(0, 0);

  f32x4 acco[2][4] = {};
  float mst[2][4], lst[2][4];
#pragma unroll
  for (int mi = 0; mi < 2; ++mi)
#pragma unroll
    for (int i = 0; i < 4; ++i) { mst[mi][i] = -1e30f; lst[mi][i] = 0.f; }

  int fr = lane & 15, fg = lane >> 4;
  int qrb = wid * 32;
  const float SCL = 0.125f * 1.44269504089f;   // 1/sqrt(D) * log2(e): exp2 domain

  for (int it = 0; it < 32; ++it) {
    __syncthreads();
    if (it < 31) stageKV((it + 1) & 1, it + 1);
    int buf = it & 1;

    // ---- S = Q K^T
    f32x4 sc[2][4] = {};
    bf16x8 qa[2][2], kb[4][2];
#pragma unroll
    for (int mi = 0; mi < 2; ++mi)
#pragma unroll
      for (int ks = 0; ks < 2; ++ks)
        qa[mi][ks] = *(const bf16x8*)&Qs[swzi(qrb + mi * 16 + fr, ks * 64 + fg * 16)];
#pragma unroll
    for (int ni = 0; ni < 4; ++ni)
#pragma unroll
      for (int ks = 0; ks < 2; ++ks)
        kb[ni][ks] = *(const bf16x8*)&Ks[buf][swzi(ni * 16 + fr, ks * 64 + fg * 16)];
#pragma unroll
    for (int mi = 0; mi < 2; ++mi)
#pragma unroll
      for (int ni = 0; ni < 4; ++ni)
#pragma unroll
        for (int ks = 0; ks < 2; ++ks)
          sc[mi][ni] = __builtin_amdgcn_mfma_f32_16x16x32_bf16(qa[mi][ks], kb[ni][ks], sc[mi][ni], 0, 0, 0);

    // ---- online softmax (exp2 domain, wave-parallel 16-lane row reduce)
    float alpha[2][4];
#pragma unroll
    for (int mi = 0; mi < 2; ++mi) {
#pragma unroll
      for (int i = 0; i < 4; ++i) {
        float s0 = sc[mi][0][i] * SCL, s1 = sc[mi][1][i] * SCL;
        float s2 = sc[mi][2][i] * SCL, s3 = sc[mi][3][i] * SCL;
        float rmax = fmaxf(fmaxf(s0, s1), fmaxf(s2, s3));
#pragma unroll
        for (int x = 1; x < 16; x <<= 1) rmax = fmaxf(rmax, __shfl_xor(rmax, x));
        float mold = mst[mi][i];
        float mnew = fmaxf(mold, rmax);
        float a_ = __builtin_amdgcn_exp2f(mold - mnew);
        float p0 = __builtin_amdgcn_exp2f(s0 - mnew), p1 = __builtin_amdgcn_exp2f(s1 - mnew);
        float p2 = __builtin_amdgcn_exp2f(s2 - mnew), p3 = __builtin_amdgcn_exp2f(s3 - mnew);
        float rsum = (p0 + p1) + (p2 + p3);
#pragma unroll
        for (int x = 1; x < 16; x <<= 1) rsum += __shfl_xor(rsum, x);
        mst[mi][i] = mnew;
        lst[mi][i] = lst[mi][i] * a_ + rsum;
        alpha[mi][i] = a_;
        int prow = qrb + mi * 16 + fg * 4 + i;
        Ps[swzi(prow, ( 0 + fr) * 2)] = f2bf(p0);
        Ps[swzi(prow, (16 + fr) * 2)] = f2bf(p1);
        Ps[swzi(prow, (32 + fr) * 2)] = f2bf(p2);
        Ps[swzi(prow, (48 + fr) * 2)] = f2bf(p3);
      }
    }
#pragma unroll
    for (int mi = 0; mi < 2; ++mi)
#pragma unroll
      for (int ni = 0; ni < 4; ++ni)
#pragma unroll
        for (int i = 0; i < 4; ++i) acco[mi][ni][i] *= alpha[mi][i];

    // ---- O += P V   (A = P from LDS, B = V^T rows)
    bf16x8 pa[2][2], vb[4][2];
#pragma unroll
    for (int mi = 0; mi < 2; ++mi)
#pragma unroll
      for (int ks = 0; ks < 2; ++ks)
        pa[mi][ks] = *(const bf16x8*)&Ps[swzi(qrb + mi * 16 + fr, ks * 64 + fg * 16)];
#pragma unroll
    for (int ni = 0; ni < 4; ++ni)
#pragma unroll
      for (int ks = 0; ks < 2; ++ks)
        vb[ni][ks] = *(const bf16x8*)&Vs[buf][swzi(ni * 16 + fr, ks * 64 + fg * 16)];
#pragma unroll
    for (int mi = 0; mi < 2; ++mi)
#pragma unroll
      for (int ni = 0; ni < 4; ++ni)
#pragma unroll
        for (int ks = 0; ks < 2; ++ks)
          acco[mi][ni] = __builtin_amdgcn_mfma_f32_16x16x32_bf16(pa[mi][ks], vb[ni][ks], acco[mi][ni], 0, 0, 0);
  }

  // ---- epilogue: O /= l, store bf16 to [b*T+t, h*64+d]
  int b = bh >> 3, h = bh & 7;
#pragma unroll
  for (int mi = 0; mi < 2; ++mi) {
#pragma unroll
    for (int i = 0; i < 4; ++i) {
      float rl = 1.0f / lst[mi][i];
#pragma unroll
      for (int ni = 0; ni < 4; ++ni) {
        int t = tt * 128 + qrb + mi * 16 + fg * 4 + i;
        int d = ni * 16 + fr;
        attno[(size_t)(b * T_ + t) * E_ + h * 64 + d] = f2bf(acco[mi][ni][i] * rl);
      }
    }
  }
}

// ---------------------------------------------------------------- launch
extern "C" void kernel_launch(void* const* d_in, const int* in_sizes, int n_in,
                              void* d_out, int out_size, void* d_ws, size_t ws_size,
                              hipStream_t stream) {
  const float* query = (const float*)d_in[0];
  const float* key_  = (const float*)d_in[1];
  const float* value = (const float*)d_in[2];
  const float* Wq    = (const float*)d_in[3];
  const float* bq    = (const float*)d_in[4];
  const float* Wk    = (const float*)d_in[5];
  const float* bk    = (const float*)d_in[6];
  const float* Wv    = (const float*)d_in[7];
  const float* bv    = (const float*)d_in[8];
  const float* Wo    = (const float*)d_in[9];
  const float* bo    = (const float*)d_in[10];
  const float* r     = (const float*)d_in[11];

  char* ws = (char*)d_ws;
  unsigned short* qb    = (unsigned short*)(ws + 0);          //  8 MiB  query bf16
  unsigned short* kb    = (unsigned short*)(ws + 8388608);    //  8 MiB  key bf16
  unsigned short* vb    = (unsigned short*)(ws + 16777216);   //  8 MiB  value bf16
  unsigned short* wqb   = (unsigned short*)(ws + 25165824);   // 512 KiB
  unsigned short* wkb   = (unsigned short*)(ws + 25690112);
  unsigned short* wvb   = (unsigned short*)(ws + 26214400);
  unsigned short* wob   = (unsigned short*)(ws + 26738688);
  unsigned short* qp    = (unsigned short*)(ws + 27262976);   //  8 MiB  [B,H,T,D]
  unsigned short* kp    = (unsigned short*)(ws + 35651584);   //  8 MiB  [B,H,S,D]
  unsigned short* vtp   = (unsigned short*)(ws + 44040192);   //  8 MiB  [B,H,D,S]
  unsigned short* attno = (unsigned short*)(ws + 52428800);   //  8 MiB  [B*T, E]

  cvt3_bf16<<<1536, 256, 0, stream>>>(query, key_, value, qb, kb, vb, (B_ * T_ * E_) / 4);
  cvt4_bf16<<<512, 256, 0, stream>>>(Wq, Wk, Wv, Wo, wqb, wkb, wvb, wob, (E_ * E_) / 4);

  // Q = logistic(query Wq^T + bq)  -> [B,H,T,D]
  gemm_nt<EPI_LH><<<256, 256, 0, stream>>>(qb, wqb, bq, qp, r, B_ * T_, E_, 4);
  // K = logistic(key Wk^T + bk)    -> [B,H,S,D]
  gemm_nt<EPI_LH><<<256, 256, 0, stream>>>(kb, wkb, bk, kp, r, B_ * S_, E_, 4);
  // V^T = Wv value^T + bv          -> [B,H,D,S]  (swapped NT gemm)
  gemm_nt<EPI_VT><<<256, 256, 0, stream>>>(wvb, vb, bv, vtp, r, E_, B_ * S_, 64);

  attn_flash<<<512, 256, 0, stream>>>(qp, kp, vtp, attno);

  // out = attno Wo^T + bo  (fp32)
  gemm_nt<EPI_F32><<<256, 256, 0, stream>>>(attno, wob, bo, d_out, r, B_ * T_, E_, 4);
}

// Round 3
// 141.026 us; speedup vs baseline: 1.5033x; 1.2453x over previous
//
#include <hip/hip_runtime.h>
#include <stdint.h>

#define B_ 4
#define T_ 2048
#define S_ 2048
#define E_ 512
#define H_ 8
#define D_ 64

using bf16x8 = __attribute__((ext_vector_type(8))) short;
using bf16x4 = __attribute__((ext_vector_type(4))) short;
using f32x4  = __attribute__((ext_vector_type(4))) float;

__device__ __forceinline__ unsigned short f2bf(float f) {
  unsigned u = __float_as_uint(f);
  u += 0x7fffu + ((u >> 16) & 1u);          // round-to-nearest-even
  return (unsigned short)(u >> 16);
}

// pack two floats to bf16 pair (round-half-up; ties differ from RNE only at exact .5 ulp)
__device__ __forceinline__ unsigned bfpair(float a, float b) {
  unsigned ua = (__float_as_uint(a) + 0x8000u) >> 16;
  unsigned ub = (__float_as_uint(b) + 0x8000u) & 0xffff0000u;
  return ua | ub;
}

__device__ __forceinline__ float sigmoidf_(float x) {
  return 1.0f / (1.0f + __expf(-x));
}

// legacy K=16 bf16 MFMA: A/B = 4 bf16 (2 VGPR), layout row=lane&15, k=(lane>>4)*4+e
__device__ __forceinline__ f32x4 mfma16x16x16(bf16x4 a, bf16x4 b, f32x4 c) {
#if __has_builtin(__builtin_amdgcn_mfma_f32_16x16x16bf16_1k)
  return __builtin_amdgcn_mfma_f32_16x16x16bf16_1k(a, b, c, 0, 0, 0);
#else
  asm("v_mfma_f32_16x16x16_bf16 %0, %1, %2, %0" : "+v"(c) : "v"(a), "v"(b));
  return c;
#endif
}

// async global->LDS, 16B per lane. LDS dest = wave-uniform base + lane*16.
__device__ __forceinline__ void gl16(const void* g, void* l) {
  __builtin_amdgcn_global_load_lds(
      (const __attribute__((address_space(1))) unsigned*)g,
      (__attribute__((address_space(3))) unsigned*)l,
      16, 0, 0);
}

// T2 swizzle for [R][64 bf16] (128B-row) LDS tiles:
// physical byte-in-row = logical byte-in-row ^ ((row&7)<<4).
__device__ __forceinline__ int swzi(int row, int ebyte) {
  return row * 64 + ((ebyte ^ ((row & 7) << 4)) >> 1);
}

// ---------------------------------------------------------------- converts
__global__ __launch_bounds__(256) void cvt3_bf16(
    const float* __restrict__ a, const float* __restrict__ b, const float* __restrict__ c,
    unsigned short* __restrict__ oa, unsigned short* __restrict__ ob,
    unsigned short* __restrict__ oc, int n4) {
  int seg = blockIdx.x >> 9;
  const float* in = (seg == 0) ? a : (seg == 1) ? b : c;
  unsigned short* out = (seg == 0) ? oa : (seg == 1) ? ob : oc;
  int i = (blockIdx.x & 511) * 256 + threadIdx.x;
  for (; i < n4; i += 512 * 256) {
    float4 v = ((const float4*)in)[i];
    ushort4 o;
    o.x = f2bf(v.x); o.y = f2bf(v.y); o.z = f2bf(v.z); o.w = f2bf(v.w);
    ((ushort4*)out)[i] = o;
  }
}

__global__ __launch_bounds__(256) void cvt4_bf16(
    const float* __restrict__ a, const float* __restrict__ b,
    const float* __restrict__ c, const float* __restrict__ d,
    unsigned short* __restrict__ oa, unsigned short* __restrict__ ob,
    unsigned short* __restrict__ oc, unsigned short* __restrict__ od, int n4) {
  int seg = blockIdx.x >> 7;
  const float* in = (seg == 0) ? a : (seg == 1) ? b : (seg == 2) ? c : d;
  unsigned short* out = (seg == 0) ? oa : (seg == 1) ? ob : (seg == 2) ? oc : od;
  int i = (blockIdx.x & 127) * 256 + threadIdx.x;
  for (; i < n4; i += 128 * 256) {
    float4 v = ((const float4*)in)[i];
    ushort4 o;
    o.x = f2bf(v.x); o.y = f2bf(v.y); o.z = f2bf(v.z); o.w = f2bf(v.w);
    ((ushort4*)out)[i] = o;
  }
}

// ---------------------------------------------------------------- GEMM
// C[M,N] = A[M,512] * W[N,512]^T  (NT gemm, K=512), 128x128 tile, BK=64.
#define EPI_LH  0
#define EPI_VT  1
#define EPI_F32 2

template <int EPI>
__global__ __launch_bounds__(256) void gemm_nt(
    const unsigned short* __restrict__ A,
    const unsigned short* __restrict__ W,
    const float* __restrict__ bias,
    void* __restrict__ outp,
    const float* __restrict__ rptr,
    float oscale,
    int M, int N, int nTN) {
  __shared__ unsigned short As[2][128 * 64];
  __shared__ unsigned short Bs[2][128 * 64];

  int tid = threadIdx.x;
  int lane = tid & 63, wid = tid >> 6;
  int bm = blockIdx.x / nTN, bn = blockIdx.x % nTN;
  int m0 = bm * 128, n0 = bn * 128;

  f32x4 acc[4][4] = {};

  int rowc = tid >> 3;                                  // tile-local row / chunk
  int kswz = ((tid & 7) ^ ((tid >> 3) & 7)) << 4;       // pre-swizzled source byte col

  auto stage = [&](int buf, int kt) {
#pragma unroll
    for (int c = 0; c < 4; ++c) {
      const char* ga = (const char*)A + (size_t)(m0 + c * 32 + rowc) * 1024 + kt * 128 + kswz;
      const char* gw = (const char*)W + (size_t)(n0 + c * 32 + rowc) * 1024 + kt * 128 + kswz;
      gl16(ga, (char*)&As[buf][0] + c * 4096 + (wid << 10));
      gl16(gw, (char*)&Bs[buf][0] + c * 4096 + (wid << 10));
    }
  };

  stage(0, 0);

  int wm = wid >> 1, wn = wid & 1;       // 2x2 waves, 64x64 each
  int fr = lane & 15, fg = lane >> 4;

  for (int kt = 0; kt < 8; ++kt) {
    __syncthreads();                     // staged tile `kt` ready (vmcnt drained)
    if (kt < 7) stage((kt + 1) & 1, kt + 1);
    int buf = kt & 1;
#pragma unroll
    for (int ks = 0; ks < 2; ++ks) {
      bf16x8 a[4], b[4];
#pragma unroll
      for (int mi = 0; mi < 4; ++mi)
        a[mi] = *(const bf16x8*)&As[buf][swzi(wm * 64 + mi * 16 + fr, ks * 64 + fg * 16)];
#pragma unroll
      for (int ni = 0; ni < 4; ++ni)
        b[ni] = *(const bf16x8*)&Bs[buf][swzi(wn * 64 + ni * 16 + fr, ks * 64 + fg * 16)];
#pragma unroll
      for (int mi = 0; mi < 4; ++mi)
#pragma unroll
        for (int ni = 0; ni < 4; ++ni)
          acc[mi][ni] = __builtin_amdgcn_mfma_f32_16x16x32_bf16(a[mi], b[ni], acc[mi][ni], 0, 0, 0);
    }
  }

  float rs = 0.f;
  if constexpr (EPI == EPI_LH) rs = 4.0f * sigmoidf_(rptr[0]) * oscale;

#pragma unroll
  for (int mi = 0; mi < 4; ++mi) {
#pragma unroll
    for (int ni = 0; ni < 4; ++ni) {
#pragma unroll
      for (int i = 0; i < 4; ++i) {
        int gm = m0 + wm * 64 + mi * 16 + fg * 4 + i;   // C row
        int gn = n0 + wn * 64 + ni * 16 + fr;           // C col
        float x = acc[mi][ni][i];
        if constexpr (EPI == EPI_LH) {
          x += bias[gn];
          float xn = sigmoidf_(x);
          float val = rs * xn * (1.0f - xn);
          int b = gm >> 11, t = gm & 2047, h = gn >> 6, d = gn & 63;
          ((unsigned short*)outp)[((size_t)(b * H_ + h) * T_ + t) * D_ + d] = f2bf(val);
        } else if constexpr (EPI == EPI_VT) {
          x += bias[gm];                                // bias indexed by e = row
          int h = gm >> 6, d = gm & 63, b = gn >> 11, s = gn & 2047;
          ((unsigned short*)outp)[((size_t)(b * H_ + h) * D_ + d) * S_ + s] = f2bf(x);
        } else {
          x += bias[gn];
          ((float*)outp)[(size_t)gm * E_ + gn] = x;
        }
      }
    }
  }
}

// ---------------------------------------------------------------- flash attention
// grid: 512 blocks = 32 (b,h) * 16 Q-tiles of 128 rows. 4 waves * 32 rows.
// Swapped QK^T (S^T = mfma(K,Q)) -> softmax row is lane-local (q = lane&15).
// PV via legacy 16x16x16 MFMA: O^T = mfma(V^T_frag, P_frag), P stays in regs.
__global__ __launch_bounds__(256) void attn_flash(
    const unsigned short* __restrict__ qp,   // [B,H,T,D], pre-scaled by 0.125*log2e
    const unsigned short* __restrict__ kp,   // [B,H,S,D]
    const unsigned short* __restrict__ vtp,  // [B,H,D,S]
    unsigned short* __restrict__ attno) {    // [B*T, E]
  __shared__ unsigned short Qs[128 * 64];
  __shared__ unsigned short Ks[2][64 * 64];
  __shared__ unsigned short Vs[2][64 * 64];  // V^T tile: [d][s]

  int tid = threadIdx.x, lane = tid & 63, wid = tid >> 6;
  int tt = blockIdx.x & 15, bh = blockIdx.x >> 4;
  const unsigned short* qh = qp + (size_t)bh * T_ * D_ + (size_t)tt * 128 * D_;
  const unsigned short* kh = kp + (size_t)bh * S_ * D_;
  const unsigned short* vh = vtp + (size_t)bh * D_ * S_;

  int kswz = ((tid & 7) ^ ((tid >> 3) & 7)) << 4;       // pre-swizzled source byte col

  // stage Q (swizzled source -> linear LDS == swizzled logical layout)
#pragma unroll
  for (int c = 0; c < 4; ++c)
    gl16((const char*)qh + (size_t)(c * 32 + (tid >> 3)) * 128 + kswz,
         (char*)Qs + c * 4096 + (wid << 10));

  auto stageKV = [&](int buf, int it) {
#pragma unroll
    for (int c = 0; c < 2; ++c)  // K tile rows: [s][64d]
      gl16((const char*)kh + (size_t)(it * 64 + c * 32 + (tid >> 3)) * 128 + kswz,
           (char*)&Ks[buf][0] + c * 4096 + (wid << 10));
#pragma unroll
    for (int c = 0; c < 2; ++c) {  // V^T tile rows: [d][64s], row stride S*2 bytes
      int d = c * 32 + (tid >> 3);
      gl16((const char*)vh + (size_t)d * (S_ * 2) + it * 128 + kswz,
           (char*)&Vs[buf][0] + c * 4096 + (wid << 10));
    }
  };

  stageKV(0, 0);

  int fr = lane & 15, fg = (lane >> 4) & 3;
  int qrb = wid * 32;

  __syncthreads();   // Q + KV(0) staged

  // hoisted loop-invariant Q fragments (B-operand of swapped QK^T)
  bf16x8 qa[2][2];
#pragma unroll
  for (int mi = 0; mi < 2; ++mi)
#pragma unroll
    for (int ks = 0; ks < 2; ++ks)
      qa[mi][ks] = *(const bf16x8*)&Qs[swzi(qrb + mi * 16 + fr, ks * 64 + fg * 16)];

  f32x4 acco[2][4] = {};            // O^T: [mi(q-tile)][nd(d-tile)]; lane: q=fr, d=16nd+4fg+reg
  float mst[2] = {-1e30f, -1e30f};  // running max per q-row (q = 16mi+fr)
  float lst[2] = {0.f, 0.f};

  union PU { unsigned u[2]; bf16x4 v; };

  for (int it = 0; it < 32; ++it) {
    __syncthreads();
    if (it < 31) stageKV((it + 1) & 1, it + 1);
    int buf = it & 1;

    // ---- S^T = K Q^T : st[ni][mi], lane holds k=16ni+4fg+reg, q=16mi+fr
    bf16x8 kb[4][2];
#pragma unroll
    for (int ni = 0; ni < 4; ++ni)
#pragma unroll
      for (int ks = 0; ks < 2; ++ks)
        kb[ni][ks] = *(const bf16x8*)&Ks[buf][swzi(ni * 16 + fr, ks * 64 + fg * 16)];

    f32x4 st[4][2] = {};
#pragma unroll
    for (int ni = 0; ni < 4; ++ni)
#pragma unroll
      for (int mi = 0; mi < 2; ++mi)
#pragma unroll
        for (int ks = 0; ks < 2; ++ks)
          st[ni][mi] = __builtin_amdgcn_mfma_f32_16x16x32_bf16(kb[ni][ks], qa[mi][ks], st[ni][mi], 0, 0, 0);

    // ---- online softmax, lane-local rows (reduce over fg groups: xor16 + xor32)
    bf16x4 pfr[2][4];
    float alpha[2];
#pragma unroll
    for (int mi = 0; mi < 2; ++mi) {
      float mx = st[0][mi][0];
#pragma unroll
      for (int ni = 0; ni < 4; ++ni)
#pragma unroll
        for (int e = 0; e < 4; ++e)
          if (ni + e) mx = fmaxf(mx, st[ni][mi][e]);
      mx = fmaxf(mx, __shfl_xor(mx, 16));
      mx = fmaxf(mx, __shfl_xor(mx, 32));
      float mnew = fmaxf(mst[mi], mx);
      alpha[mi] = __builtin_amdgcn_exp2f(mst[mi] - mnew);
      mst[mi] = mnew;
      float sum = 0.f;
#pragma unroll
      for (int ni = 0; ni < 4; ++ni) {
        float p0 = __builtin_amdgcn_exp2f(st[ni][mi][0] - mnew);
        float p1 = __builtin_amdgcn_exp2f(st[ni][mi][1] - mnew);
        float p2 = __builtin_amdgcn_exp2f(st[ni][mi][2] - mnew);
        float p3 = __builtin_amdgcn_exp2f(st[ni][mi][3] - mnew);
        sum += (p0 + p1) + (p2 + p3);
        PU pu;
        pu.u[0] = bfpair(p0, p1);
        pu.u[1] = bfpair(p2, p3);
        pfr[mi][ni] = pu.v;
      }
      sum += __shfl_xor(sum, 16);
      sum += __shfl_xor(sum, 32);
      lst[mi] = lst[mi] * alpha[mi] + sum;
    }

#pragma unroll
    for (int mi = 0; mi < 2; ++mi)
#pragma unroll
      for (int nd = 0; nd < 4; ++nd)
#pragma unroll
        for (int e = 0; e < 4; ++e) acco[mi][nd][e] *= alpha[mi];

    // ---- O^T += V^T P^T : A = V^T[d][s] frag (4 bf16), B = P frag (in regs)
#pragma unroll
    for (int nd = 0; nd < 4; ++nd) {
      const char* vrow = (const char*)&Vs[buf][0] + (nd * 16 + fr) * 128;
#pragma unroll
      for (int ni = 0; ni < 4; ++ni) {
        int vcolb = (ni * 32 + fg * 8) ^ ((fr & 7) << 4);
        bf16x4 vf = *(const bf16x4*)(vrow + vcolb);
#pragma unroll
        for (int mi = 0; mi < 2; ++mi)
          acco[mi][nd] = mfma16x16x16(vf, pfr[mi][ni], acco[mi][nd]);
      }
    }
  }

  // ---- epilogue: O^T lane holds q=16mi+fr, d=16nd+4fg+reg; divide by l, pack 8B stores
  int b = bh >> 3, h = bh & 7;
#pragma unroll
  for (int mi = 0; mi < 2; ++mi) {
    float rl = 1.0f / lst[mi];
    int t = tt * 128 + qrb + mi * 16 + fr;
    unsigned short* rowp = attno + (size_t)(b * T_ + t) * E_ + h * 64;
#pragma unroll
    for (int nd = 0; nd < 4; ++nd) {
      ushort4 o;
      o.x = f2bf(acco[mi][nd][0] * rl);
      o.y = f2bf(acco[mi][nd][1] * rl);
      o.z = f2bf(acco[mi][nd][2] * rl);
      o.w = f2bf(acco[mi][nd][3] * rl);
      *(ushort4*)(rowp + nd * 16 + fg * 4) = o;
    }
  }
}

// ---------------------------------------------------------------- launch
extern "C" void kernel_launch(void* const* d_in, const int* in_sizes, int n_in,
                              void* d_out, int out_size, void* d_ws, size_t ws_size,
                              hipStream_t stream) {
  const float* query = (const float*)d_in[0];
  const float* key_  = (const float*)d_in[1];
  const float* value = (const float*)d_in[2];
  const float* Wq    = (const float*)d_in[3];
  const float* bq    = (const float*)d_in[4];
  const float* Wk    = (const float*)d_in[5];
  const float* bk    = (const float*)d_in[6];
  const float* Wv    = (const float*)d_in[7];
  const float* bv    = (const float*)d_in[8];
  const float* Wo    = (const float*)d_in[9];
  const float* bo    = (const float*)d_in[10];
  const float* r     = (const float*)d_in[11];

  char* ws = (char*)d_ws;
  unsigned short* qb    = (unsigned short*)(ws + 0);          //  8 MiB  query bf16
  unsigned short* kb    = (unsigned short*)(ws + 8388608);    //  8 MiB  key bf16
  unsigned short* vb    = (unsigned short*)(ws + 16777216);   //  8 MiB  value bf16
  unsigned short* wqb   = (unsigned short*)(ws + 25165824);   // 512 KiB
  unsigned short* wkb   = (unsigned short*)(ws + 25690112);
  unsigned short* wvb   = (unsigned short*)(ws + 26214400);
  unsigned short* wob   = (unsigned short*)(ws + 26738688);
  unsigned short* qp    = (unsigned short*)(ws + 27262976);   //  8 MiB  [B,H,T,D]
  unsigned short* kp    = (unsigned short*)(ws + 35651584);   //  8 MiB  [B,H,S,D]
  unsigned short* vtp   = (unsigned short*)(ws + 44040192);   //  8 MiB  [B,H,D,S]
  unsigned short* attno = (unsigned short*)(ws + 52428800);   //  8 MiB  [B*T, E]

  cvt3_bf16<<<1536, 256, 0, stream>>>(query, key_, value, qb, kb, vb, (B_ * T_ * E_) / 4);
  cvt4_bf16<<<512, 256, 0, stream>>>(Wq, Wk, Wv, Wo, wqb, wkb, wvb, wob, (E_ * E_) / 4);

  const float SCLQ = 0.125f * 1.44269504089f;  // fold 1/sqrt(D) * log2(e) into Q

  // Q = logistic(query Wq^T + bq) * SCLQ  -> [B,H,T,D]
  gemm_nt<EPI_LH><<<256, 256, 0, stream>>>(qb, wqb, bq, qp, r, SCLQ, B_ * T_, E_, 4);
  // K = logistic(key Wk^T + bk)           -> [B,H,S,D]
  gemm_nt<EPI_LH><<<256, 256, 0, stream>>>(kb, wkb, bk, kp, r, 1.0f, B_ * S_, E_, 4);
  // V^T = Wv value^T + bv                 -> [B,H,D,S]  (swapped NT gemm)
  gemm_nt<EPI_VT><<<256, 256, 0, stream>>>(wvb, vb, bv, vtp, r, 1.0f, E_, B_ * S_, 64);

  attn_flash<<<512, 256, 0, stream>>>(qp, kp, vtp, attno);

  // out = attno Wo^T + bo  (fp32)
  gemm_nt<EPI_F32><<<256, 256, 0, stream>>>(attno, wob, bo, d_out, r, 1.0f, B_ * T_, E_, 4);
}